// Round 11
// baseline (667.852 us; speedup 1.0000x reference)
//
#include <hip/hip_runtime.h>
#include <math.h>

// Problem constants
#define BATCH 256
#define TT    2048
#define CC    39
#define CP    40        // padded channel stride (bf16)
#define Y1ST  44        // y1 LDS row stride (shorts)
#define NBLK  8
#define KK    2
#define NCLS  8
#define BN_EPS 1e-5f
#define TBLK  512       // 8 waves
#define NW    8

typedef __attribute__((ext_vector_type(8))) short short8;
typedef __attribute__((ext_vector_type(4))) float floatx4;

__device__ __forceinline__ unsigned short f2b(float f) {
    union { float f; unsigned u; } v; v.f = f;
    unsigned r = v.u + 0x7FFF + ((v.u >> 16) & 1);   // RNE
    return (unsigned short)(r >> 16);
}
__device__ __forceinline__ unsigned cvtpk(float lo, float hi) {
    unsigned r;
    asm("v_cvt_pk_bf16_f32 %0, %1, %2" : "=v"(r) : "v"(lo), "v"(hi));
    return r;
}
__device__ __forceinline__ float blo(unsigned u) {
    union { unsigned v; float f; } k; k.v = u << 16; return k.f;
}
__device__ __forceinline__ float bhi(unsigned u) {
    union { unsigned v; float f; } k; k.v = u & 0xffff0000u; return k.f;
}
__device__ __forceinline__ void gl_lds16(const void* g, void* l) {
    __builtin_amdgcn_global_load_lds(
        (const __attribute__((address_space(1))) unsigned int*)g,
        (__attribute__((address_space(3))) unsigned int*)l, 16, 0, 0);
}

// Weight fragment sizes (A-operand layout: row=co, K=96 in 3 slices)
#define WFB_PER   (2*3*3*512)
#define WFB_TOTAL (2*NBLK*WFB_PER)
#define BFB_TOTAL (2*NBLK*2*48)
#define WFF_TOTAL (3*2*512)
#define BFF_TOTAL 48
#define ZPAD_SHORTS (256 * CP)

// ---------------------------------------------------------------------------
// Fold BN into conv weights (A-operand fragments). Unchanged (proven).
// ---------------------------------------------------------------------------
__global__ void fold_kernel(const float* __restrict__ fw_w, const float* __restrict__ fw_b,
                            const float* __restrict__ fw_g, const float* __restrict__ fw_be,
                            const float* __restrict__ fw_m, const float* __restrict__ fw_v,
                            const float* __restrict__ bw_w, const float* __restrict__ bw_b,
                            const float* __restrict__ bw_g, const float* __restrict__ bw_be,
                            const float* __restrict__ bw_m, const float* __restrict__ bw_v,
                            const float* __restrict__ c1w, const float* __restrict__ c1b,
                            unsigned short* __restrict__ wfb, float* __restrict__ bfb,
                            unsigned short* __restrict__ wff, float* __restrict__ bff) {
    int idx = blockIdx.x * blockDim.x + threadIdx.x;
    if (idx < WFB_TOTAL) {
        int i = idx;
        int reg = i & 7;   i >>= 3;
        int lane = i & 63; i >>= 6;
        int sl = i % 3;    i /= 3;
        int ct = i % 3;    i /= 3;
        int layer = i & 1; i >>= 1;
        int blk = i & 7;   i >>= 3;
        int dir = i;
        int g = lane >> 4;
        int co = ct * 16 + (lane & 15);
        int p, ci; bool ok = true;
        if (sl < 2) {
            int kin = (g << 3) + reg;
            p = kin >> 4;
            ci = sl * 16 + (kin & 15);
        } else {
            p = g & 1;
            ci = 32 + reg;
            ok = (g < 2);
        }
        float val = 0.f;
        if (ok && co < CC && ci < CC) {
            const float* w = dir ? bw_w : fw_w;
            const float* gam = dir ? bw_g : fw_g;
            const float* var = dir ? bw_v : fw_v;
            int il = blk * 2 + layer;
            float sc = gam[il * CC + co] * rsqrtf(var[il * CC + co] + BN_EPS);
            val = w[((size_t)(il * CC + co) * CC + ci) * KK + p] * sc;
        }
        wfb[idx] = f2b(val);
        return;
    }
    idx -= WFB_TOTAL;
    if (idx < BFB_TOTAL) {
        int co = idx % 48;
        int i = idx / 48;
        int layer = i & 1; i >>= 1;
        int blk = i & 7;   i >>= 3;
        int dir = i;
        float val = 0.f;
        if (co < CC) {
            const float* b  = dir ? bw_b  : fw_b;
            const float* g  = dir ? bw_g  : fw_g;
            const float* be = dir ? bw_be : fw_be;
            const float* m  = dir ? bw_m  : fw_m;
            const float* v  = dir ? bw_v  : fw_v;
            int r = (blk * 2 + layer) * CC + co;
            float sc = g[r] * rsqrtf(v[r] + BN_EPS);
            val = (b[r] - m[r]) * sc + be[r];
        }
        bfb[idx] = val;
        return;
    }
    idx -= BFB_TOTAL;
    if (idx < WFF_TOTAL) {
        int i = idx;
        int reg = i & 7;   i >>= 3;
        int lane = i & 63; i >>= 6;
        int sl = i & 1;    i >>= 1;
        int ct = i;
        int co = ct * 16 + (lane & 15);
        int ci = sl * 32 + ((lane >> 4) << 3) + reg;
        float val = (co < CC && ci < CC) ? c1w[co * CC + ci] : 0.f;
        wff[idx] = f2b(val);
        return;
    }
    idx -= WFF_TOTAL;
    if (idx < BFF_TOTAL) {
        bff[idx] = (idx < CC) ? c1b[idx] : 0.f;
    }
}

// ---------------------------------------------------------------------------
// Level-0 block with fused front 1x1 conv (unchanged from passing R10).
// ---------------------------------------------------------------------------
__global__ __launch_bounds__(TBLK) void block0_mfma(
        const float* __restrict__ in,
        const unsigned short* __restrict__ wf_all, const float* __restrict__ bf_all,
        const unsigned short* __restrict__ wff, const float* __restrict__ bff,
        unsigned short* __restrict__ yg, float* __restrict__ skipPart) {
    constexpr int D = 1;
    constexpr int ROWS_X   = 272;
    constexpr int XT_SHORTS = ROWS_X * CP;
    constexpr int M1       = 17;
    constexpr int ROWS_REAL = 256 + D;
    constexpr int Y1_SHORTS = M1 * 16 * Y1ST + 8;
    constexpr int M2W      = 256 / (16 * NW);

    extern __shared__ char ldsraw[];
    unsigned short* xt = (unsigned short*)ldsraw;
    unsigned short* y1 = xt + XT_SHORTS;
    float* stash = (float*)(y1 + Y1_SHORTS);

    const int dir = blockIdx.z, b = blockIdx.y, tile = blockIdx.x;
    const int t0 = tile * 256;
    const int tid = threadIdx.x, lane = tid & 63, wave = tid >> 6;
    const int c = lane & 15, g = lane >> 4;
    const size_t cbase = (size_t)(dir * BATCH + b) * TT * CP;

    {
        unsigned* xd = (unsigned*)xt;
        const float* inb = in + (size_t)b * TT * CC;
        for (int e = tid; e < ROWS_X * 20; e += TBLK) {
            int row = e / 20, cp = e - row * 20;
            int t = t0 - 2 + row;
            unsigned val = 0u;
            if (t >= 0 && row < 258) {
                int srow = dir ? (TT - 1 - t) : t;
                const float* sp = inb + (size_t)srow * CC + cp * 2;
                float f0 = sp[0];
                float f1 = (cp < 19) ? sp[1] : 0.f;
                val = cvtpk(f0, f1);
            }
            xd[e] = val;
        }
        if (tid < 16) ((unsigned*)(xt + XT_SHORTS))[tid] = 0;
    }

    short8 FW[3][2];
    float fbs[3][4];
#pragma unroll
    for (int ct = 0; ct < 3; ++ct) {
#pragma unroll
        for (int sl = 0; sl < 2; ++sl)
            FW[ct][sl] = *(const short8*)(wff + (((ct * 2 + sl) * 64 + lane) << 3));
#pragma unroll
        for (int j = 0; j < 4; ++j) fbs[ct][j] = bff[ct * 16 + g * 4 + j];
    }
    __syncthreads();

    for (int mt = wave; mt < M1; mt += NW) {
        int row = (mt << 4) + c;
        const unsigned short* bp = xt + row * CP;
        floatx4 acc[3];
#pragma unroll
        for (int ct = 0; ct < 3; ++ct)
            acc[ct] = floatx4{fbs[ct][0], fbs[ct][1], fbs[ct][2], fbs[ct][3]};
#pragma unroll
        for (int sl = 0; sl < 2; ++sl) {
            short8 B = *(const short8*)(bp + sl * 32 + g * 8);
#pragma unroll
            for (int ct = 0; ct < 3; ++ct)
                acc[ct] = __builtin_amdgcn_mfma_f32_16x16x32_bf16(FW[ct][sl], B, acc[ct], 0, 0, 0);
        }
        unsigned short* op = xt + row * CP;
#pragma unroll
        for (int ct = 0; ct < 3; ++ct) {
            if (ct == 2 && g >= 2) continue;
            uint2 v;
            v.x = cvtpk(acc[ct][0], acc[ct][1]);
            v.y = cvtpk(acc[ct][2], acc[ct][3]);
            *(uint2*)(op + ct * 16 + g * 4) = v;
        }
    }
    __syncthreads();

    const int r01off = (g >> 1) * D;
    const int r2off  = (g & 1) * D;
    const int koff8  = (g & 1) << 3;
    const unsigned short* wf = wf_all + (size_t)(dir * NBLK + 0) * WFB_PER;
    const float* bf = bf_all + (size_t)(dir * NBLK + 0) * 96;

    short8 Wf[3][3];
    float bs[3][4];
#pragma unroll
    for (int ct = 0; ct < 3; ++ct) {
#pragma unroll
        for (int sl = 0; sl < 3; ++sl)
            Wf[ct][sl] = *(const short8*)(wf + (((ct * 3 + sl) * 64 + lane) << 3));
#pragma unroll
        for (int j = 0; j < 4; ++j) bs[ct][j] = bf[ct * 16 + g * 4 + j];
    }

    for (int mt = wave; mt < M1; mt += NW) {
        int j0 = mt << 4;
        const unsigned short* bp01 = xt + (j0 + c + r01off) * CP + koff8;
        const unsigned short* bp2  = xt + (j0 + c + r2off) * CP + 32;
        short8 B0 = *(const short8*)(bp01);
        short8 B1 = *(const short8*)(bp01 + 16);
        short8 B2 = *(const short8*)(bp2);
        floatx4 acc[3];
#pragma unroll
        for (int ct = 0; ct < 3; ++ct) {
            acc[ct] = floatx4{bs[ct][0], bs[ct][1], bs[ct][2], bs[ct][3]};
            acc[ct] = __builtin_amdgcn_mfma_f32_16x16x32_bf16(Wf[ct][0], B0, acc[ct], 0, 0, 0);
            acc[ct] = __builtin_amdgcn_mfma_f32_16x16x32_bf16(Wf[ct][1], B1, acc[ct], 0, 0, 0);
            acc[ct] = __builtin_amdgcn_mfma_f32_16x16x32_bf16(Wf[ct][2], B2, acc[ct], 0, 0, 0);
        }
        int r = j0 + c;
        bool dead = (t0 - D + r < 0) || (r >= ROWS_REAL);
        unsigned short* yp = y1 + r * Y1ST;
#pragma unroll
        for (int ct = 0; ct < 3; ++ct) {
            if (ct == 2 && g >= 2) continue;
            uint2 v;
            v.x = cvtpk(fmaxf(acc[ct][0], 0.f), fmaxf(acc[ct][1], 0.f));
            v.y = cvtpk(fmaxf(acc[ct][2], 0.f), fmaxf(acc[ct][3], 0.f));
            if (dead) { v.x = 0u; v.y = 0u; }
            *(uint2*)(yp + ct * 16 + g * 4) = v;
        }
    }
    __syncthreads();

#pragma unroll
    for (int ct = 0; ct < 3; ++ct) {
#pragma unroll
        for (int sl = 0; sl < 3; ++sl)
            Wf[ct][sl] = *(const short8*)(wf + ((((3 + ct) * 3 + sl) * 64 + lane) << 3));
#pragma unroll
        for (int j = 0; j < 4; ++j) bs[ct][j] = bf[48 + ct * 16 + g * 4 + j];
    }

    float sums[3][4];
#pragma unroll
    for (int ct = 0; ct < 3; ++ct)
#pragma unroll
        for (int j = 0; j < 4; ++j) sums[ct][j] = 0.f;

#pragma unroll
    for (int mi = 0; mi < M2W; ++mi) {
        int j0 = (((wave * M2W) + mi) << 4);
        const unsigned short* bp01 = y1 + (j0 + c + r01off) * Y1ST + koff8;
        const unsigned short* bp2  = y1 + (j0 + c + r2off) * Y1ST + 32;
        short8 B0 = *(const short8*)(bp01);
        short8 B1 = *(const short8*)(bp01 + 16);
        short8 B2 = *(const short8*)(bp2);
        floatx4 acc[3];
#pragma unroll
        for (int ct = 0; ct < 3; ++ct) {
            acc[ct] = floatx4{bs[ct][0], bs[ct][1], bs[ct][2], bs[ct][3]};
            acc[ct] = __builtin_amdgcn_mfma_f32_16x16x32_bf16(Wf[ct][0], B0, acc[ct], 0, 0, 0);
            acc[ct] = __builtin_amdgcn_mfma_f32_16x16x32_bf16(Wf[ct][1], B1, acc[ct], 0, 0, 0);
            acc[ct] = __builtin_amdgcn_mfma_f32_16x16x32_bf16(Wf[ct][2], B2, acc[ct], 0, 0, 0);
        }
        int r = j0 + c;
        const unsigned short* xrow = xt + (r + 2 * D) * CP;
        unsigned short* orow = yg + cbase + (size_t)(t0 + r) * CP;
#pragma unroll
        for (int ct = 0; ct < 3; ++ct) {
            uint2 xv = *(const uint2*)(xrow + ct * 16 + g * 4);
            float g0 = blo(xv.x) * __builtin_amdgcn_rcpf(1.f + __expf(-acc[ct][0]));
            float g1 = bhi(xv.x) * __builtin_amdgcn_rcpf(1.f + __expf(-acc[ct][1]));
            float g2 = blo(xv.y) * __builtin_amdgcn_rcpf(1.f + __expf(-acc[ct][2]));
            float g3 = bhi(xv.y) * __builtin_amdgcn_rcpf(1.f + __expf(-acc[ct][3]));
            sums[ct][0] += g0; sums[ct][1] += g1;
            sums[ct][2] += g2; sums[ct][3] += g3;
            if (!(ct == 2 && g >= 2)) {
                uint2 v;
                v.x = cvtpk(g0, g1);
                v.y = cvtpk(g2, g3);
                *(uint2*)(orow + ct * 16 + g * 4) = v;
            }
        }
    }
#pragma unroll
    for (int ct = 0; ct < 3; ++ct)
#pragma unroll
        for (int j = 0; j < 4; ++j) {
            float v = sums[ct][j];
            v += __shfl_xor(v, 1, 64);
            v += __shfl_xor(v, 2, 64);
            v += __shfl_xor(v, 4, 64);
            v += __shfl_xor(v, 8, 64);
            sums[ct][j] = v;
        }
    if (c == 0) {
#pragma unroll
        for (int ct = 0; ct < 3; ++ct)
#pragma unroll
            for (int j = 0; j < 4; ++j)
                stash[wave * 48 + ct * 16 + g * 4 + j] = sums[ct][j];
    }
    __syncthreads();
    if (tid < CC) {
        float s = 0.f;
#pragma unroll
        for (int w = 0; w < NW; ++w) s += stash[w * 48 + tid];
        skipPart[(((size_t)(0 * 2 + dir) * BATCH + b) * CC + tid) * 16 + tile] = s;
    }
}

// ---------------------------------------------------------------------------
// PAIR kernel: two consecutive levels (dilations DA, DB=2*DA) fused in LDS.
// Proven mechanisms only: global staging + zpad, separate buffers, dead-mask
// writes constant zero (never consumes acc), stage pattern identical to
// block_mfma with generalized windows:
//   X    rows [0,RXA) <-> times t0-HX+row      (HX = 2DB+2DA)
//   y1a  rows [0,M1A*16), real RYA = T+HYA     (HYA = 2DB+DA)
//   AOUT rows [0,RAA),   real RAR = T+2DB
//   y1b  rows [0,M1B*16), real RYB = T+DB
// ---------------------------------------------------------------------------
template <int DA, int DB, int LA, int TtC>
__global__ __launch_bounds__(TBLK) void pair_mfma(
        const unsigned short* __restrict__ xg, unsigned short* __restrict__ yg,
        const unsigned short* __restrict__ wf_all, const float* __restrict__ bf_all,
        float* __restrict__ skipPart, const unsigned short* __restrict__ zpad) {
    constexpr int HX  = 2 * DB + 2 * DA;
    constexpr int HYA = 2 * DB + DA;
    constexpr int RXR = TtC + HX;
    constexpr int RYA = TtC + HYA;
    constexpr int M1A = (RYA + 15) / 16;
    constexpr int RXA = M1A * 16 + DA;            // alloc rows (tail zpad-staged)
    constexpr int RYB = TtC + DB;
    constexpr int M1B = (RYB + 15) / 16;
    constexpr int RAR = TtC + 2 * DB;
    constexpr int RAA = ((M1B * 16 + DB + 15) / 16) * 16;
    constexpr int M2A = RAA / 16;
    constexpr int M2B = TtC / (16 * NW);
    constexpr int XSH  = RXA * CP;
    constexpr int Y1SH = M1A * 16 * Y1ST + 8;
    constexpr int ASH  = RAA * CP;
    constexpr int NCHA = RXA * 5;
    constexpr int NIT  = (NCHA + TBLK - 1) / TBLK;
    constexpr int NTIL = TT / TtC;

    extern __shared__ char ldsraw[];
    unsigned short* X  = (unsigned short*)ldsraw;     // [RXA][CP]
    unsigned short* Y1 = X + XSH;                     // [M1A*16][Y1ST]
    unsigned short* AO = Y1 + Y1SH;                   // [RAA][CP]
    float* stash = (float*)(AO + ASH);                // [NW][48]

    const int dir = blockIdx.z, b = blockIdx.y, tile = blockIdx.x;
    const int t0 = tile * TtC;
    const int tid = threadIdx.x, lane = tid & 63, wave = tid >> 6;
    const int c = lane & 15, g = lane >> 4;
    const int koff8 = (g & 1) << 3;
    const int oa01 = (g >> 1) * DA, oa2 = (g & 1) * DA;
    const int ob01 = (g >> 1) * DB, ob2 = (g & 1) * DB;

    const size_t cbase = (size_t)(dir * BATCH + b) * TT * CP;
    const unsigned short* wfa = wf_all + (size_t)(dir * NBLK + LA) * WFB_PER;
    const float* bfa = bf_all + (size_t)(dir * NBLK + LA) * 96;
    const unsigned short* wfb2 = wf_all + (size_t)(dir * NBLK + LA + 1) * WFB_PER;
    const float* bfb2 = bf_all + (size_t)(dir * NBLK + LA + 1) * 96;

    // ---- async stage X rows [t0-HX, ...) ; zpad for t<0 and alloc tail ----
    {
        const unsigned short* gx = xg + cbase;
#pragma unroll
        for (int it = 0; it < NIT; ++it) {
            int chunk = it * TBLK + wave * 64 + lane;
            if (chunk < NCHA) {
                unsigned row = (unsigned)chunk / 5u;
                int sub = chunk - (int)row * 5;
                int t = t0 - HX + (int)row;
                const unsigned short* src = (t >= 0 && (int)row < RXR)
                    ? (gx + (size_t)t * CP + sub * 8)
                    : (zpad + ((row & 255u) * CP + sub * 8));
                gl_lds16(src, X + (size_t)(it * TBLK + wave * 64) * 8);
            }
        }
    }

    short8 Wf[3][3];
    float bs[3][4];
#pragma unroll
    for (int ct = 0; ct < 3; ++ct) {
#pragma unroll
        for (int sl = 0; sl < 3; ++sl)
            Wf[ct][sl] = *(const short8*)(wfa + (((ct * 3 + sl) * 64 + lane) << 3));
#pragma unroll
        for (int j = 0; j < 4; ++j) bs[ct][j] = bfa[ct * 16 + g * 4 + j];
    }
    __syncthreads();

    // ---- stage 1a: y1a = relu(conv1a(X)) ----
    for (int mt = wave; mt < M1A; mt += NW) {
        int j0 = mt << 4;
        const unsigned short* bp01 = X + (j0 + c + oa01) * CP + koff8;
        const unsigned short* bp2  = X + (j0 + c + oa2) * CP + 32;
        short8 B0 = *(const short8*)(bp01);
        short8 B1 = *(const short8*)(bp01 + 16);
        short8 B2 = *(const short8*)(bp2);
        floatx4 acc[3];
#pragma unroll
        for (int ct = 0; ct < 3; ++ct) {
            acc[ct] = floatx4{bs[ct][0], bs[ct][1], bs[ct][2], bs[ct][3]};
            acc[ct] = __builtin_amdgcn_mfma_f32_16x16x32_bf16(Wf[ct][0], B0, acc[ct], 0, 0, 0);
            acc[ct] = __builtin_amdgcn_mfma_f32_16x16x32_bf16(Wf[ct][1], B1, acc[ct], 0, 0, 0);
            acc[ct] = __builtin_amdgcn_mfma_f32_16x16x32_bf16(Wf[ct][2], B2, acc[ct], 0, 0, 0);
        }
        int r = j0 + c;
        bool dead = (t0 - HYA + r < 0) || (r >= RYA);
        unsigned short* yp = Y1 + r * Y1ST;
#pragma unroll
        for (int ct = 0; ct < 3; ++ct) {
            if (ct == 2 && g >= 2) continue;
            uint2 v;
            v.x = cvtpk(fmaxf(acc[ct][0], 0.f), fmaxf(acc[ct][1], 0.f));
            v.y = cvtpk(fmaxf(acc[ct][2], 0.f), fmaxf(acc[ct][3], 0.f));
            if (dead) { v.x = 0u; v.y = 0u; }
            *(uint2*)(yp + ct * 16 + g * 4) = v;
        }
    }
    __syncthreads();

    // ---- stage 2a: AOUT = X * sigmoid(conv2a(y1a)); skip-a partials ----
#pragma unroll
    for (int ct = 0; ct < 3; ++ct) {
#pragma unroll
        for (int sl = 0; sl < 3; ++sl)
            Wf[ct][sl] = *(const short8*)(wfa + ((((3 + ct) * 3 + sl) * 64 + lane) << 3));
#pragma unroll
        for (int j = 0; j < 4; ++j) bs[ct][j] = bfa[48 + ct * 16 + g * 4 + j];
    }

    float sums[3][4];
#pragma unroll
    for (int ct = 0; ct < 3; ++ct)
#pragma unroll
        for (int j = 0; j < 4; ++j) sums[ct][j] = 0.f;

    for (int mt = wave; mt < M2A; mt += NW) {
        int j0 = mt << 4;
        const unsigned short* bp01 = Y1 + (j0 + c + oa01) * Y1ST + koff8;
        const unsigned short* bp2  = Y1 + (j0 + c + oa2) * Y1ST + 32;
        short8 B0 = *(const short8*)(bp01);
        short8 B1 = *(const short8*)(bp01 + 16);
        short8 B2 = *(const short8*)(bp2);
        floatx4 acc[3];
#pragma unroll
        for (int ct = 0; ct < 3; ++ct) {
            acc[ct] = floatx4{bs[ct][0], bs[ct][1], bs[ct][2], bs[ct][3]};
            acc[ct] = __builtin_amdgcn_mfma_f32_16x16x32_bf16(Wf[ct][0], B0, acc[ct], 0, 0, 0);
            acc[ct] = __builtin_amdgcn_mfma_f32_16x16x32_bf16(Wf[ct][1], B1, acc[ct], 0, 0, 0);
            acc[ct] = __builtin_amdgcn_mfma_f32_16x16x32_bf16(Wf[ct][2], B2, acc[ct], 0, 0, 0);
        }
        int ra = j0 + c;
        bool adead = (ra >= RAR);
        bool inskip = (ra >= 2 * DB) && (ra < 2 * DB + TtC);
        const unsigned short* xrow = X + (ra + 2 * DA) * CP;
        unsigned short* arow = AO + ra * CP;
#pragma unroll
        for (int ct = 0; ct < 3; ++ct) {
            if (ct == 2 && g >= 2) continue;
            uint2 ov;
            if (adead) {
                ov.x = 0u; ov.y = 0u;
            } else {
                uint2 xv = *(const uint2*)(xrow + ct * 16 + g * 4);
                float g0 = blo(xv.x) * __builtin_amdgcn_rcpf(1.f + __expf(-acc[ct][0]));
                float g1 = bhi(xv.x) * __builtin_amdgcn_rcpf(1.f + __expf(-acc[ct][1]));
                float g2 = blo(xv.y) * __builtin_amdgcn_rcpf(1.f + __expf(-acc[ct][2]));
                float g3 = bhi(xv.y) * __builtin_amdgcn_rcpf(1.f + __expf(-acc[ct][3]));
                if (inskip) {
                    sums[ct][0] += g0; sums[ct][1] += g1;
                    sums[ct][2] += g2; sums[ct][3] += g3;
                }
                ov.x = cvtpk(g0, g1);
                ov.y = cvtpk(g2, g3);
            }
            *(uint2*)(arow + ct * 16 + g * 4) = ov;
        }
    }
#pragma unroll
    for (int ct = 0; ct < 3; ++ct)
#pragma unroll
        for (int j = 0; j < 4; ++j) {
            float v = sums[ct][j];
            v += __shfl_xor(v, 1, 64);
            v += __shfl_xor(v, 2, 64);
            v += __shfl_xor(v, 4, 64);
            v += __shfl_xor(v, 8, 64);
            sums[ct][j] = v;
        }
    if (c == 0) {
#pragma unroll
        for (int ct = 0; ct < 3; ++ct)
#pragma unroll
            for (int j = 0; j < 4; ++j)
                stash[wave * 48 + ct * 16 + g * 4 + j] = sums[ct][j];
    }
    __syncthreads();
    if (tid < CC) {
        float s = 0.f;
#pragma unroll
        for (int w = 0; w < NW; ++w) s += stash[w * 48 + tid];
        skipPart[(((size_t)(LA * 2 + dir) * BATCH + b) * CC + tid) * 16 + tile] = s;
    }

    // ---- stage 1b: y1b = relu(conv1b(AOUT)) (overwrites Y1) ----
#pragma unroll
    for (int ct = 0; ct < 3; ++ct) {
#pragma unroll
        for (int sl = 0; sl < 3; ++sl)
            Wf[ct][sl] = *(const short8*)(wfb2 + (((ct * 3 + sl) * 64 + lane) << 3));
#pragma unroll
        for (int j = 0; j < 4; ++j) bs[ct][j] = bfb2[ct * 16 + g * 4 + j];
    }
    for (int mt = wave; mt < M1B; mt += NW) {
        int j0 = mt << 4;
        const unsigned short* bp01 = AO + (j0 + c + ob01) * CP + koff8;
        const unsigned short* bp2  = AO + (j0 + c + ob2) * CP + 32;
        short8 B0 = *(const short8*)(bp01);
        short8 B1 = *(const short8*)(bp01 + 16);
        short8 B2 = *(const short8*)(bp2);
        floatx4 acc[3];
#pragma unroll
        for (int ct = 0; ct < 3; ++ct) {
            acc[ct] = floatx4{bs[ct][0], bs[ct][1], bs[ct][2], bs[ct][3]};
            acc[ct] = __builtin_amdgcn_mfma_f32_16x16x32_bf16(Wf[ct][0], B0, acc[ct], 0, 0, 0);
            acc[ct] = __builtin_amdgcn_mfma_f32_16x16x32_bf16(Wf[ct][1], B1, acc[ct], 0, 0, 0);
            acc[ct] = __builtin_amdgcn_mfma_f32_16x16x32_bf16(Wf[ct][2], B2, acc[ct], 0, 0, 0);
        }
        int r = j0 + c;
        bool dead = (t0 - DB + r < 0) || (r >= RYB);
        unsigned short* yp = Y1 + r * Y1ST;
#pragma unroll
        for (int ct = 0; ct < 3; ++ct) {
            if (ct == 2 && g >= 2) continue;
            uint2 v;
            v.x = cvtpk(fmaxf(acc[ct][0], 0.f), fmaxf(acc[ct][1], 0.f));
            v.y = cvtpk(fmaxf(acc[ct][2], 0.f), fmaxf(acc[ct][3], 0.f));
            if (dead) { v.x = 0u; v.y = 0u; }
            *(uint2*)(yp + ct * 16 + g * 4) = v;
        }
    }
    __syncthreads();

    // ---- stage 2b: out = AOUT * sigmoid(conv2b(y1b)) -> global; skip-b ----
#pragma unroll
    for (int ct = 0; ct < 3; ++ct) {
#pragma unroll
        for (int sl = 0; sl < 3; ++sl)
            Wf[ct][sl] = *(const short8*)(wfb2 + ((((3 + ct) * 3 + sl) * 64 + lane) << 3));
#pragma unroll
        for (int j = 0; j < 4; ++j) bs[ct][j] = bfb2[48 + ct * 16 + g * 4 + j];
    }
#pragma unroll
    for (int ct = 0; ct < 3; ++ct)
#pragma unroll
        for (int j = 0; j < 4; ++j) sums[ct][j] = 0.f;

#pragma unroll
    for (int mi = 0; mi < M2B; ++mi) {
        int j0 = (wave * M2B + mi) << 4;
        const unsigned short* bp01 = Y1 + (j0 + c + ob01) * Y1ST + koff8;
        const unsigned short* bp2  = Y1 + (j0 + c + ob2) * Y1ST + 32;
        short8 B0 = *(const short8*)(bp01);
        short8 B1 = *(const short8*)(bp01 + 16);
        short8 B2 = *(const short8*)(bp2);
        floatx4 acc[3];
#pragma unroll
        for (int ct = 0; ct < 3; ++ct) {
            acc[ct] = floatx4{bs[ct][0], bs[ct][1], bs[ct][2], bs[ct][3]};
            acc[ct] = __builtin_amdgcn_mfma_f32_16x16x32_bf16(Wf[ct][0], B0, acc[ct], 0, 0, 0);
            acc[ct] = __builtin_amdgcn_mfma_f32_16x16x32_bf16(Wf[ct][1], B1, acc[ct], 0, 0, 0);
            acc[ct] = __builtin_amdgcn_mfma_f32_16x16x32_bf16(Wf[ct][2], B2, acc[ct], 0, 0, 0);
        }
        int rb = j0 + c;
        const unsigned short* arow = AO + (rb + 2 * DB) * CP;
        unsigned short* orow = yg + cbase + (size_t)(t0 + rb) * CP;
#pragma unroll
        for (int ct = 0; ct < 3; ++ct) {
            uint2 xv = *(const uint2*)(arow + ct * 16 + g * 4);
            float g0 = blo(xv.x) * __builtin_amdgcn_rcpf(1.f + __expf(-acc[ct][0]));
            float g1 = bhi(xv.x) * __builtin_amdgcn_rcpf(1.f + __expf(-acc[ct][1]));
            float g2 = blo(xv.y) * __builtin_amdgcn_rcpf(1.f + __expf(-acc[ct][2]));
            float g3 = bhi(xv.y) * __builtin_amdgcn_rcpf(1.f + __expf(-acc[ct][3]));
            sums[ct][0] += g0; sums[ct][1] += g1;
            sums[ct][2] += g2; sums[ct][3] += g3;
            if (!(ct == 2 && g >= 2)) {
                uint2 v;
                v.x = cvtpk(g0, g1);
                v.y = cvtpk(g2, g3);
                *(uint2*)(orow + ct * 16 + g * 4) = v;
            }
        }
    }
#pragma unroll
    for (int ct = 0; ct < 3; ++ct)
#pragma unroll
        for (int j = 0; j < 4; ++j) {
            float v = sums[ct][j];
            v += __shfl_xor(v, 1, 64);
            v += __shfl_xor(v, 2, 64);
            v += __shfl_xor(v, 4, 64);
            v += __shfl_xor(v, 8, 64);
            sums[ct][j] = v;
        }
    if (c == 0) {
#pragma unroll
        for (int ct = 0; ct < 3; ++ct)
#pragma unroll
            for (int j = 0; j < 4; ++j)
                stash[wave * 48 + ct * 16 + g * 4 + j] = sums[ct][j];
    }
    __syncthreads();
    if (tid < CC) {
        float s = 0.f;
#pragma unroll
        for (int w = 0; w < NW; ++w) s += stash[w * 48 + tid];
        skipPart[(((size_t)((LA + 1) * 2 + dir) * BATCH + b) * CC + tid) * 16 + tile] = s;
    }
}

static inline size_t pair_lds(int DA, int DB, int T) {
    int HYA = 2 * DB + DA;
    int M1A = (T + HYA + 15) / 16;
    int RXA = M1A * 16 + DA;
    int M1B = (T + DB + 15) / 16;
    int RAA = ((M1B * 16 + DB + 15) / 16) * 16;
    return (size_t)(RXA * CP + M1A * 16 * Y1ST + 8 + RAA * CP) * 2 + NW * 48 * 4;
}

// ---------------------------------------------------------------------------
// Single-level block (unchanged from passing R6/R10).
// ---------------------------------------------------------------------------
template <int D, int TtC>
__global__ __launch_bounds__(TBLK) void block_mfma(const unsigned short* __restrict__ xg,
                                                   unsigned short* __restrict__ yg,
                                                   const unsigned short* __restrict__ wf_all,
                                                   const float* __restrict__ bf_all,
                                                   float* __restrict__ skipPart,
                                                   const unsigned short* __restrict__ zpad,
                                                   int blk, int writeOut) {
    constexpr int NW_      = TBLK / 64;
    constexpr int ROWS_X   = TtC + 2 * D;
    constexpr int NCH      = ROWS_X * 5;
    constexpr int NIT      = (NCH + TBLK - 1) / TBLK;
    constexpr int XT_SHORTS = ROWS_X * CP;
    constexpr int M1       = (TtC + D + 15) / 16;
    constexpr int ROWS_REAL = TtC + D;
    constexpr int Y1_SHORTS = M1 * 16 * Y1ST + 8;
    constexpr int M2W      = TtC / (16 * NW_);

    extern __shared__ char ldsraw[];
    unsigned short* xt = (unsigned short*)ldsraw;
    unsigned short* y1 = xt + XT_SHORTS;
    float* stash = (float*)(y1 + Y1_SHORTS);

    const int dir = blockIdx.z, b = blockIdx.y, tile = blockIdx.x;
    const int t0 = tile * TtC;
    const int tid = threadIdx.x, lane = tid & 63, wave = tid >> 6;
    const int c = lane & 15, g = lane >> 4;

    const size_t cbase = (size_t)(dir * BATCH + b) * TT * CP;
    const unsigned short* wf = wf_all + (size_t)(dir * NBLK + blk) * WFB_PER;
    const float* bf = bf_all + (size_t)(dir * NBLK + blk) * 96;

    {
        const unsigned short* gx = xg + cbase;
#pragma unroll
        for (int it = 0; it < NIT; ++it) {
            int chunk = it * TBLK + wave * 64 + lane;
            if (chunk < NCH) {
                unsigned row = (unsigned)chunk / 5u;
                int sub = chunk - (int)row * 5;
                int t = t0 - 2 * D + (int)row;
                const unsigned short* src = (t >= 0)
                    ? (gx + (size_t)t * CP + sub * 8)
                    : (zpad + (row * CP + sub * 8));
                gl_lds16(src, xt + (size_t)(it * TBLK + wave * 64) * 8);
            }
        }
    }

    short8 Wf[3][3];
#pragma unroll
    for (int ct = 0; ct < 3; ++ct)
#pragma unroll
        for (int sl = 0; sl < 3; ++sl)
            Wf[ct][sl] = *(const short8*)(wf + ((((0 * 3 + ct) * 3 + sl) * 64 + lane) << 3));
    float bs[3][4];
#pragma unroll
    for (int ct = 0; ct < 3; ++ct)
#pragma unroll
        for (int j = 0; j < 4; ++j) bs[ct][j] = bf[ct * 16 + g * 4 + j];

    __syncthreads();

    const int r01off = (g >> 1) * D;
    const int r2off  = (g & 1) * D;
    const int koff8  = (g & 1) << 3;

    for (int mt = wave; mt < M1; mt += NW_) {
        int j0 = mt << 4;
        const unsigned short* bp01 = xt + (j0 + c + r01off) * CP + koff8;
        const unsigned short* bp2  = xt + (j0 + c + r2off) * CP + 32;
        short8 B0 = *(const short8*)(bp01);
        short8 B1 = *(const short8*)(bp01 + 16);
        short8 B2 = *(const short8*)(bp2);
        floatx4 acc[3];
#pragma unroll
        for (int ct = 0; ct < 3; ++ct) {
            acc[ct] = floatx4{bs[ct][0], bs[ct][1], bs[ct][2], bs[ct][3]};
            acc[ct] = __builtin_amdgcn_mfma_f32_16x16x32_bf16(Wf[ct][0], B0, acc[ct], 0, 0, 0);
            acc[ct] = __builtin_amdgcn_mfma_f32_16x16x32_bf16(Wf[ct][1], B1, acc[ct], 0, 0, 0);
            acc[ct] = __builtin_amdgcn_mfma_f32_16x16x32_bf16(Wf[ct][2], B2, acc[ct], 0, 0, 0);
        }
        int r = j0 + c;
        bool dead = (t0 - D + r < 0) || (r >= ROWS_REAL);
        unsigned short* yp = y1 + r * Y1ST;
#pragma unroll
        for (int ct = 0; ct < 3; ++ct) {
            if (ct == 2 && g >= 2) continue;
            uint2 v;
            v.x = cvtpk(fmaxf(acc[ct][0], 0.f), fmaxf(acc[ct][1], 0.f));
            v.y = cvtpk(fmaxf(acc[ct][2], 0.f), fmaxf(acc[ct][3], 0.f));
            if (dead) { v.x = 0u; v.y = 0u; }
            *(uint2*)(yp + ct * 16 + g * 4) = v;
        }
    }
    __syncthreads();

#pragma unroll
    for (int ct = 0; ct < 3; ++ct)
#pragma unroll
        for (int sl = 0; sl < 3; ++sl)
            Wf[ct][sl] = *(const short8*)(wf + ((((1 * 3 + ct) * 3 + sl) * 64 + lane) << 3));
#pragma unroll
    for (int ct = 0; ct < 3; ++ct)
#pragma unroll
        for (int j = 0; j < 4; ++j) bs[ct][j] = bf[48 + ct * 16 + g * 4 + j];

    float sums[3][4];
#pragma unroll
    for (int ct = 0; ct < 3; ++ct)
#pragma unroll
        for (int j = 0; j < 4; ++j) sums[ct][j] = 0.f;

#pragma unroll
    for (int mi = 0; mi < M2W; ++mi) {
        int j0 = (wave * M2W + mi) << 4;
        const unsigned short* bp01 = y1 + (j0 + c + r01off) * Y1ST + koff8;
        const unsigned short* bp2  = y1 + (j0 + c + r2off) * Y1ST + 32;
        short8 B0 = *(const short8*)(bp01);
        short8 B1 = *(const short8*)(bp01 + 16);
        short8 B2 = *(const short8*)(bp2);
        floatx4 acc[3];
#pragma unroll
        for (int ct = 0; ct < 3; ++ct) {
            acc[ct] = floatx4{bs[ct][0], bs[ct][1], bs[ct][2], bs[ct][3]};
            acc[ct] = __builtin_amdgcn_mfma_f32_16x16x32_bf16(Wf[ct][0], B0, acc[ct], 0, 0, 0);
            acc[ct] = __builtin_amdgcn_mfma_f32_16x16x32_bf16(Wf[ct][1], B1, acc[ct], 0, 0, 0);
            acc[ct] = __builtin_amdgcn_mfma_f32_16x16x32_bf16(Wf[ct][2], B2, acc[ct], 0, 0, 0);
        }
        int r = j0 + c;
        const unsigned short* xrow = xt + (r + 2 * D) * CP;
        unsigned short* orow = yg + cbase + (size_t)(t0 + r) * CP;
#pragma unroll
        for (int ct = 0; ct < 3; ++ct) {
            uint2 xv = *(const uint2*)(xrow + ct * 16 + g * 4);
            float g0 = blo(xv.x) * __builtin_amdgcn_rcpf(1.f + __expf(-acc[ct][0]));
            float g1 = bhi(xv.x) * __builtin_amdgcn_rcpf(1.f + __expf(-acc[ct][1]));
            float g2 = blo(xv.y) * __builtin_amdgcn_rcpf(1.f + __expf(-acc[ct][2]));
            float g3 = bhi(xv.y) * __builtin_amdgcn_rcpf(1.f + __expf(-acc[ct][3]));
            sums[ct][0] += g0; sums[ct][1] += g1;
            sums[ct][2] += g2; sums[ct][3] += g3;
            if (writeOut && !(ct == 2 && g >= 2)) {
                uint2 v;
                v.x = cvtpk(g0, g1);
                v.y = cvtpk(g2, g3);
                *(uint2*)(orow + ct * 16 + g * 4) = v;
            }
        }
    }
#pragma unroll
    for (int ct = 0; ct < 3; ++ct)
#pragma unroll
        for (int j = 0; j < 4; ++j) {
            float v = sums[ct][j];
            v += __shfl_xor(v, 1, 64);
            v += __shfl_xor(v, 2, 64);
            v += __shfl_xor(v, 4, 64);
            v += __shfl_xor(v, 8, 64);
            sums[ct][j] = v;
        }
    if (c == 0) {
#pragma unroll
        for (int ct = 0; ct < 3; ++ct)
#pragma unroll
            for (int j = 0; j < 4; ++j)
                stash[wave * 48 + ct * 16 + g * 4 + j] = sums[ct][j];
    }
    __syncthreads();
    if (tid < CC) {
        float s = 0.f;
#pragma unroll
        for (int w = 0; w < NW_; ++w) s += stash[w * 48 + tid];
        skipPart[(((size_t)(blk * 2 + dir) * BATCH + b) * CC + tid) * 16 + tile] = s;
    }
}

static inline size_t lds_bytes_for(int D, int Tt) {
    int rows_x = Tt + 2 * D;
    int xt_shorts = rows_x * CP;
    int m1 = (Tt + D + 15) / 16;
    int y1_shorts = m1 * 16 * Y1ST + 8;
    return (size_t)(xt_shorts + y1_shorts) * 2 + (TBLK / 64) * 48 * 4;
}

// ---------------------------------------------------------------------------
// Tail: sums ALL 16 tile slots (pairs use 16 tiles; others 8 + zeros).
// ---------------------------------------------------------------------------
__global__ __launch_bounds__(64) void tail_kernel(const float* __restrict__ skipPart,
                                                  const float* __restrict__ wl,
                                                  const float* __restrict__ cw,
                                                  const float* __restrict__ cb,
                                                  float* __restrict__ out) {
    __shared__ float xs[CC];
    int b = blockIdx.x;
    int cth = threadIdx.x;
    if (cth < CC) {
        float x2 = 0.f;
        for (int i = 0; i < NBLK; ++i) {
            float wli = wl[i] * (1.0f / TT);
            for (int dirn = 0; dirn < 2; ++dirn) {
                const float* sp = skipPart + (((size_t)(i * 2 + dirn) * BATCH + b) * CC + cth) * 16;
                float s = 0.f;
#pragma unroll
                for (int tl = 0; tl < 16; ++tl) s += sp[tl];
                x2 = fmaf(s, wli, x2);
            }
        }
        xs[cth] = x2;
    }
    __syncthreads();
    if (threadIdx.x == 0) {
        float lg[NCLS];
        float mx = -1e30f;
        for (int o = 0; o < NCLS; ++o) {
            float a = cb[o];
#pragma unroll
            for (int cc2 = 0; cc2 < CC; ++cc2) a = fmaf(cw[o * CC + cc2], xs[cc2], a);
            lg[o] = a;
            mx = fmaxf(mx, a);
        }
        float se = 0.f;
        for (int o = 0; o < NCLS; ++o) se += expf(lg[o] - mx);
        float lse = logf(se) + mx;
        for (int o = 0; o < NCLS; ++o) out[b * NCLS + o] = lg[o] - lse;
    }
}

// ---------------------------------------------------------------------------
extern "C" void kernel_launch(void* const* d_in, const int* in_sizes, int n_in,
                              void* d_out, int out_size, void* d_ws, size_t ws_size,
                              hipStream_t stream) {
    const float* inputs = (const float*)d_in[0];
    const float* c1w    = (const float*)d_in[1];
    const float* c1b    = (const float*)d_in[2];
    const float* fw_w   = (const float*)d_in[3];
    const float* fw_b   = (const float*)d_in[4];
    const float* fw_g   = (const float*)d_in[5];
    const float* fw_be  = (const float*)d_in[6];
    const float* fw_m   = (const float*)d_in[7];
    const float* fw_v   = (const float*)d_in[8];
    const float* bw_w   = (const float*)d_in[9];
    const float* bw_b   = (const float*)d_in[10];
    const float* bw_g   = (const float*)d_in[11];
    const float* bw_be  = (const float*)d_in[12];
    const float* bw_m   = (const float*)d_in[13];
    const float* bw_v   = (const float*)d_in[14];
    const float* wl     = (const float*)d_in[15];
    const float* clsw   = (const float*)d_in[16];
    const float* clsb   = (const float*)d_in[17];

    const size_t bufsz = (size_t)2 * BATCH * TT * CP;
    unsigned short* buf0 = (unsigned short*)d_ws;
    unsigned short* buf1 = buf0 + bufsz;
    float* skip = (float*)(buf1 + bufsz);
    const size_t skipsz = (size_t)NBLK * 2 * BATCH * CC * 16;
    unsigned short* wfb = (unsigned short*)(skip + skipsz);
    float* bfb = (float*)(wfb + WFB_TOTAL);
    unsigned short* wff = (unsigned short*)(bfb + BFB_TOTAL);
    float* bff = (float*)(wff + WFF_TOTAL);
    unsigned short* zpad = (unsigned short*)(bff + BFF_TOTAL);

    hipMemsetAsync(zpad, 0, ZPAD_SHORTS * sizeof(unsigned short), stream);
    hipMemsetAsync(skip, 0, skipsz * sizeof(float), stream);

    {
        int tot = WFB_TOTAL + BFB_TOTAL + WFF_TOTAL + BFF_TOTAL;
        fold_kernel<<<(tot + 255) / 256, 256, 0, stream>>>(
            fw_w, fw_b, fw_g, fw_be, fw_m, fw_v,
            bw_w, bw_b, bw_g, bw_be, bw_m, bw_v, c1w, c1b,
            wfb, bfb, wff, bff);
    }

    // level 0 with fused front conv: raw f32 -> buf0
    {
        size_t lds0 = (size_t)(272 * CP + 17 * 16 * Y1ST + 8) * 2 + (TBLK / 64) * 48 * 4 + 64;
        block0_mfma<<<dim3(TT / 256, BATCH, 2), TBLK, lds0, stream>>>(
            inputs, wfb, bfb, wff, bff, buf0, skip);
    }

    // pair levels 1+2 (d=2,4) at T=128: buf0 -> buf1
    pair_mfma<2, 4, 1, 128><<<dim3(TT / 128, BATCH, 2), TBLK, pair_lds(2, 4, 128), stream>>>(
        buf0, buf1, wfb, bfb, skip, zpad);
    // pair levels 3+4 (d=8,16) at T=128: buf1 -> buf0
    pair_mfma<8, 16, 3, 128><<<dim3(TT / 128, BATCH, 2), TBLK, pair_lds(8, 16, 128), stream>>>(
        buf1, buf0, wfb, bfb, skip, zpad);

    // singles: 32, 64, 128
    block_mfma<32, 256><<<dim3(TT / 256, BATCH, 2), TBLK, lds_bytes_for(32, 256), stream>>>(
        buf0, buf1, wfb, bfb, skip, zpad, 5, 1);
    block_mfma<64, 256><<<dim3(TT / 256, BATCH, 2), TBLK, lds_bytes_for(64, 256), stream>>>(
        buf1, buf0, wfb, bfb, skip, zpad, 6, 1);
    block_mfma<128, 256><<<dim3(TT / 256, BATCH, 2), TBLK, lds_bytes_for(128, 256), stream>>>(
        buf0, buf1, wfb, bfb, skip, zpad, 7, 0);

    tail_kernel<<<BATCH, 64, 0, stream>>>(skip, wl, clsw, clsb, (float*)d_out);
}

// Round 12
// 621.905 us; speedup vs baseline: 1.0739x; 1.0739x over previous
//
#include <hip/hip_runtime.h>
#include <math.h>

// Problem constants
#define BATCH 256
#define TT    2048
#define CC    39
#define CP    40        // padded channel stride (bf16)
#define Y1ST  44        // y1 stride in single-level kernels (proven)
#define NBLK  8
#define KK    2
#define NCLS  8
#define BN_EPS 1e-5f
#define TBLK  512       // 8 waves
#define NW    8

typedef __attribute__((ext_vector_type(8))) short short8;
typedef __attribute__((ext_vector_type(4))) float floatx4;

__device__ __forceinline__ unsigned short f2b(float f) {
    union { float f; unsigned u; } v; v.f = f;
    unsigned r = v.u + 0x7FFF + ((v.u >> 16) & 1);   // RNE
    return (unsigned short)(r >> 16);
}
__device__ __forceinline__ unsigned cvtpk(float lo, float hi) {
    unsigned r;
    asm("v_cvt_pk_bf16_f32 %0, %1, %2" : "=v"(r) : "v"(lo), "v"(hi));
    return r;
}
__device__ __forceinline__ float blo(unsigned u) {
    union { unsigned v; float f; } k; k.v = u << 16; return k.f;
}
__device__ __forceinline__ float bhi(unsigned u) {
    union { unsigned v; float f; } k; k.v = u & 0xffff0000u; return k.f;
}
__device__ __forceinline__ void gl_lds16(const void* g, void* l) {
    __builtin_amdgcn_global_load_lds(
        (const __attribute__((address_space(1))) unsigned int*)g,
        (__attribute__((address_space(3))) unsigned int*)l, 16, 0, 0);
}

#define WFB_PER   (2*3*3*512)
#define WFB_TOTAL (2*NBLK*WFB_PER)
#define BFB_TOTAL (2*NBLK*2*48)
#define WFF_TOTAL (3*2*512)
#define BFF_TOTAL 48
#define ZPAD_SHORTS (256 * CP)

// ---------------------------------------------------------------------------
// Fold BN into conv weights (A-operand fragments). Proven, unchanged.
// ---------------------------------------------------------------------------
__global__ void fold_kernel(const float* __restrict__ fw_w, const float* __restrict__ fw_b,
                            const float* __restrict__ fw_g, const float* __restrict__ fw_be,
                            const float* __restrict__ fw_m, const float* __restrict__ fw_v,
                            const float* __restrict__ bw_w, const float* __restrict__ bw_b,
                            const float* __restrict__ bw_g, const float* __restrict__ bw_be,
                            const float* __restrict__ bw_m, const float* __restrict__ bw_v,
                            const float* __restrict__ c1w, const float* __restrict__ c1b,
                            unsigned short* __restrict__ wfb, float* __restrict__ bfb,
                            unsigned short* __restrict__ wff, float* __restrict__ bff) {
    int idx = blockIdx.x * blockDim.x + threadIdx.x;
    if (idx < WFB_TOTAL) {
        int i = idx;
        int reg = i & 7;   i >>= 3;
        int lane = i & 63; i >>= 6;
        int sl = i % 3;    i /= 3;
        int ct = i % 3;    i /= 3;
        int layer = i & 1; i >>= 1;
        int blk = i & 7;   i >>= 3;
        int dir = i;
        int g = lane >> 4;
        int co = ct * 16 + (lane & 15);
        int p, ci; bool ok = true;
        if (sl < 2) {
            int kin = (g << 3) + reg;
            p = kin >> 4;
            ci = sl * 16 + (kin & 15);
        } else {
            p = g & 1;
            ci = 32 + reg;
            ok = (g < 2);
        }
        float val = 0.f;
        if (ok && co < CC && ci < CC) {
            const float* w = dir ? bw_w : fw_w;
            const float* gam = dir ? bw_g : fw_g;
            const float* var = dir ? bw_v : fw_v;
            int il = blk * 2 + layer;
            float sc = gam[il * CC + co] * rsqrtf(var[il * CC + co] + BN_EPS);
            val = w[((size_t)(il * CC + co) * CC + ci) * KK + p] * sc;
        }
        wfb[idx] = f2b(val);
        return;
    }
    idx -= WFB_TOTAL;
    if (idx < BFB_TOTAL) {
        int co = idx % 48;
        int i = idx / 48;
        int layer = i & 1; i >>= 1;
        int blk = i & 7;   i >>= 3;
        int dir = i;
        float val = 0.f;
        if (co < CC) {
            const float* b  = dir ? bw_b  : fw_b;
            const float* g  = dir ? bw_g  : fw_g;
            const float* be = dir ? bw_be : fw_be;
            const float* m  = dir ? bw_m  : fw_m;
            const float* v  = dir ? bw_v  : fw_v;
            int r = (blk * 2 + layer) * CC + co;
            float sc = g[r] * rsqrtf(v[r] + BN_EPS);
            val = (b[r] - m[r]) * sc + be[r];
        }
        bfb[idx] = val;
        return;
    }
    idx -= BFB_TOTAL;
    if (idx < WFF_TOTAL) {
        int i = idx;
        int reg = i & 7;   i >>= 3;
        int lane = i & 63; i >>= 6;
        int sl = i & 1;    i >>= 1;
        int ct = i;
        int co = ct * 16 + (lane & 15);
        int ci = sl * 32 + ((lane >> 4) << 3) + reg;
        float val = (co < CC && ci < CC) ? c1w[co * CC + ci] : 0.f;
        wff[idx] = f2b(val);
        return;
    }
    idx -= WFF_TOTAL;
    if (idx < BFF_TOTAL) {
        bff[idx] = (idx < CC) ? c1b[idx] : 0.f;
    }
}

// ---------------------------------------------------------------------------
// Level-0 block with fused front 1x1 conv (proven, unchanged from R10).
// ---------------------------------------------------------------------------
__global__ __launch_bounds__(TBLK) void block0_mfma(
        const float* __restrict__ in,
        const unsigned short* __restrict__ wf_all, const float* __restrict__ bf_all,
        const unsigned short* __restrict__ wff, const float* __restrict__ bff,
        unsigned short* __restrict__ yg, float* __restrict__ skipPart) {
    constexpr int D = 1;
    constexpr int ROWS_X   = 272;
    constexpr int XT_SHORTS = ROWS_X * CP;
    constexpr int M1       = 17;
    constexpr int ROWS_REAL = 256 + D;
    constexpr int Y1_SHORTS = M1 * 16 * Y1ST + 8;
    constexpr int M2W      = 256 / (16 * NW);

    extern __shared__ char ldsraw[];
    unsigned short* xt = (unsigned short*)ldsraw;
    unsigned short* y1 = xt + XT_SHORTS;
    float* stash = (float*)(y1 + Y1_SHORTS);

    const int dir = blockIdx.z, b = blockIdx.y, tile = blockIdx.x;
    const int t0 = tile * 256;
    const int tid = threadIdx.x, lane = tid & 63, wave = tid >> 6;
    const int c = lane & 15, g = lane >> 4;
    const size_t cbase = (size_t)(dir * BATCH + b) * TT * CP;

    {
        unsigned* xd = (unsigned*)xt;
        const float* inb = in + (size_t)b * TT * CC;
        for (int e = tid; e < ROWS_X * 20; e += TBLK) {
            int row = e / 20, cp = e - row * 20;
            int t = t0 - 2 + row;
            unsigned val = 0u;
            if (t >= 0 && row < 258) {
                int srow = dir ? (TT - 1 - t) : t;
                const float* sp = inb + (size_t)srow * CC + cp * 2;
                float f0 = sp[0];
                float f1 = (cp < 19) ? sp[1] : 0.f;
                val = cvtpk(f0, f1);
            }
            xd[e] = val;
        }
        if (tid < 16) ((unsigned*)(xt + XT_SHORTS))[tid] = 0;
    }

    short8 FW[3][2];
    float fbs[3][4];
#pragma unroll
    for (int ct = 0; ct < 3; ++ct) {
#pragma unroll
        for (int sl = 0; sl < 2; ++sl)
            FW[ct][sl] = *(const short8*)(wff + (((ct * 2 + sl) * 64 + lane) << 3));
#pragma unroll
        for (int j = 0; j < 4; ++j) fbs[ct][j] = bff[ct * 16 + g * 4 + j];
    }
    __syncthreads();

    for (int mt = wave; mt < M1; mt += NW) {
        int row = (mt << 4) + c;
        const unsigned short* bp = xt + row * CP;
        floatx4 acc[3];
#pragma unroll
        for (int ct = 0; ct < 3; ++ct)
            acc[ct] = floatx4{fbs[ct][0], fbs[ct][1], fbs[ct][2], fbs[ct][3]};
#pragma unroll
        for (int sl = 0; sl < 2; ++sl) {
            short8 B = *(const short8*)(bp + sl * 32 + g * 8);
#pragma unroll
            for (int ct = 0; ct < 3; ++ct)
                acc[ct] = __builtin_amdgcn_mfma_f32_16x16x32_bf16(FW[ct][sl], B, acc[ct], 0, 0, 0);
        }
        unsigned short* op = xt + row * CP;
#pragma unroll
        for (int ct = 0; ct < 3; ++ct) {
            if (ct == 2 && g >= 2) continue;
            uint2 v;
            v.x = cvtpk(acc[ct][0], acc[ct][1]);
            v.y = cvtpk(acc[ct][2], acc[ct][3]);
            *(uint2*)(op + ct * 16 + g * 4) = v;
        }
    }
    __syncthreads();

    const int r01off = (g >> 1) * D;
    const int r2off  = (g & 1) * D;
    const int koff8  = (g & 1) << 3;
    const unsigned short* wf = wf_all + (size_t)(dir * NBLK + 0) * WFB_PER;
    const float* bf = bf_all + (size_t)(dir * NBLK + 0) * 96;

    short8 Wf[3][3];
    float bs[3][4];
#pragma unroll
    for (int ct = 0; ct < 3; ++ct) {
#pragma unroll
        for (int sl = 0; sl < 3; ++sl)
            Wf[ct][sl] = *(const short8*)(wf + (((ct * 3 + sl) * 64 + lane) << 3));
#pragma unroll
        for (int j = 0; j < 4; ++j) bs[ct][j] = bf[ct * 16 + g * 4 + j];
    }

    for (int mt = wave; mt < M1; mt += NW) {
        int j0 = mt << 4;
        const unsigned short* bp01 = xt + (j0 + c + r01off) * CP + koff8;
        const unsigned short* bp2  = xt + (j0 + c + r2off) * CP + 32;
        short8 B0 = *(const short8*)(bp01);
        short8 B1 = *(const short8*)(bp01 + 16);
        short8 B2 = *(const short8*)(bp2);
        floatx4 acc[3];
#pragma unroll
        for (int ct = 0; ct < 3; ++ct) {
            acc[ct] = floatx4{bs[ct][0], bs[ct][1], bs[ct][2], bs[ct][3]};
            acc[ct] = __builtin_amdgcn_mfma_f32_16x16x32_bf16(Wf[ct][0], B0, acc[ct], 0, 0, 0);
            acc[ct] = __builtin_amdgcn_mfma_f32_16x16x32_bf16(Wf[ct][1], B1, acc[ct], 0, 0, 0);
            acc[ct] = __builtin_amdgcn_mfma_f32_16x16x32_bf16(Wf[ct][2], B2, acc[ct], 0, 0, 0);
        }
        int r = j0 + c;
        bool dead = (t0 - D + r < 0) || (r >= ROWS_REAL);
        unsigned short* yp = y1 + r * Y1ST;
#pragma unroll
        for (int ct = 0; ct < 3; ++ct) {
            if (ct == 2 && g >= 2) continue;
            uint2 v;
            v.x = cvtpk(fmaxf(acc[ct][0], 0.f), fmaxf(acc[ct][1], 0.f));
            v.y = cvtpk(fmaxf(acc[ct][2], 0.f), fmaxf(acc[ct][3], 0.f));
            if (dead) { v.x = 0u; v.y = 0u; }
            *(uint2*)(yp + ct * 16 + g * 4) = v;
        }
    }
    __syncthreads();

#pragma unroll
    for (int ct = 0; ct < 3; ++ct) {
#pragma unroll
        for (int sl = 0; sl < 3; ++sl)
            Wf[ct][sl] = *(const short8*)(wf + ((((3 + ct) * 3 + sl) * 64 + lane) << 3));
#pragma unroll
        for (int j = 0; j < 4; ++j) bs[ct][j] = bf[48 + ct * 16 + g * 4 + j];
    }

    float sums[3][4];
#pragma unroll
    for (int ct = 0; ct < 3; ++ct)
#pragma unroll
        for (int j = 0; j < 4; ++j) sums[ct][j] = 0.f;

#pragma unroll
    for (int mi = 0; mi < M2W; ++mi) {
        int j0 = (((wave * M2W) + mi) << 4);
        const unsigned short* bp01 = y1 + (j0 + c + r01off) * Y1ST + koff8;
        const unsigned short* bp2  = y1 + (j0 + c + r2off) * Y1ST + 32;
        short8 B0 = *(const short8*)(bp01);
        short8 B1 = *(const short8*)(bp01 + 16);
        short8 B2 = *(const short8*)(bp2);
        floatx4 acc[3];
#pragma unroll
        for (int ct = 0; ct < 3; ++ct) {
            acc[ct] = floatx4{bs[ct][0], bs[ct][1], bs[ct][2], bs[ct][3]};
            acc[ct] = __builtin_amdgcn_mfma_f32_16x16x32_bf16(Wf[ct][0], B0, acc[ct], 0, 0, 0);
            acc[ct] = __builtin_amdgcn_mfma_f32_16x16x32_bf16(Wf[ct][1], B1, acc[ct], 0, 0, 0);
            acc[ct] = __builtin_amdgcn_mfma_f32_16x16x32_bf16(Wf[ct][2], B2, acc[ct], 0, 0, 0);
        }
        int r = j0 + c;
        const unsigned short* xrow = xt + (r + 2 * D) * CP;
        unsigned short* orow = yg + cbase + (size_t)(t0 + r) * CP;
#pragma unroll
        for (int ct = 0; ct < 3; ++ct) {
            uint2 xv = *(const uint2*)(xrow + ct * 16 + g * 4);
            float g0 = blo(xv.x) * __builtin_amdgcn_rcpf(1.f + __expf(-acc[ct][0]));
            float g1 = bhi(xv.x) * __builtin_amdgcn_rcpf(1.f + __expf(-acc[ct][1]));
            float g2 = blo(xv.y) * __builtin_amdgcn_rcpf(1.f + __expf(-acc[ct][2]));
            float g3 = bhi(xv.y) * __builtin_amdgcn_rcpf(1.f + __expf(-acc[ct][3]));
            sums[ct][0] += g0; sums[ct][1] += g1;
            sums[ct][2] += g2; sums[ct][3] += g3;
            if (!(ct == 2 && g >= 2)) {
                uint2 v;
                v.x = cvtpk(g0, g1);
                v.y = cvtpk(g2, g3);
                *(uint2*)(orow + ct * 16 + g * 4) = v;
            }
        }
    }
#pragma unroll
    for (int ct = 0; ct < 3; ++ct)
#pragma unroll
        for (int j = 0; j < 4; ++j) {
            float v = sums[ct][j];
            v += __shfl_xor(v, 1, 64);
            v += __shfl_xor(v, 2, 64);
            v += __shfl_xor(v, 4, 64);
            v += __shfl_xor(v, 8, 64);
            sums[ct][j] = v;
        }
    if (c == 0) {
#pragma unroll
        for (int ct = 0; ct < 3; ++ct)
#pragma unroll
            for (int j = 0; j < 4; ++j)
                stash[wave * 48 + ct * 16 + g * 4 + j] = sums[ct][j];
    }
    __syncthreads();
    if (tid < CC) {
        float s = 0.f;
#pragma unroll
        for (int w = 0; w < NW; ++w) s += stash[w * 48 + tid];
        skipPart[(((size_t)(0 * 2 + dir) * BATCH + b) * CC + tid) * 16 + tile] = s;
    }
}

// ---------------------------------------------------------------------------
// conv helpers for the 2-tile pipelined kernel (y1 stride = 40 shorts)
// ---------------------------------------------------------------------------
template <int D, int M1, int ROWS_REAL>
__device__ __forceinline__ void conv1_tile(
        const unsigned short* __restrict__ xt, unsigned short* __restrict__ y1,
        const unsigned short* __restrict__ wf, const float* __restrict__ bf,
        int t0, int wave, int lane) {
    const int c = lane & 15, g = lane >> 4;
    const int koff8 = (g & 1) << 3;
    const int r01off = (g >> 1) * D;
    const int r2off  = (g & 1) * D;
    short8 Wf[3][3]; float bs[3][4];
#pragma unroll
    for (int ct = 0; ct < 3; ++ct) {
#pragma unroll
        for (int sl = 0; sl < 3; ++sl)
            Wf[ct][sl] = *(const short8*)(wf + (((ct * 3 + sl) * 64 + lane) << 3));
#pragma unroll
        for (int j = 0; j < 4; ++j) bs[ct][j] = bf[ct * 16 + g * 4 + j];
    }
    for (int mt = wave; mt < M1; mt += NW) {
        int j0 = mt << 4;
        const unsigned short* bp01 = xt + (j0 + c + r01off) * CP + koff8;
        const unsigned short* bp2  = xt + (j0 + c + r2off) * CP + 32;
        short8 B0 = *(const short8*)(bp01);
        short8 B1 = *(const short8*)(bp01 + 16);
        short8 B2 = *(const short8*)(bp2);
        floatx4 acc[3];
#pragma unroll
        for (int ct = 0; ct < 3; ++ct) {
            acc[ct] = floatx4{bs[ct][0], bs[ct][1], bs[ct][2], bs[ct][3]};
            acc[ct] = __builtin_amdgcn_mfma_f32_16x16x32_bf16(Wf[ct][0], B0, acc[ct], 0, 0, 0);
            acc[ct] = __builtin_amdgcn_mfma_f32_16x16x32_bf16(Wf[ct][1], B1, acc[ct], 0, 0, 0);
            acc[ct] = __builtin_amdgcn_mfma_f32_16x16x32_bf16(Wf[ct][2], B2, acc[ct], 0, 0, 0);
        }
        int r = j0 + c;
        bool dead = (t0 - D + r < 0) || (r >= ROWS_REAL);
        unsigned short* yp = y1 + r * 40;
#pragma unroll
        for (int ct = 0; ct < 3; ++ct) {
            if (ct == 2 && g >= 2) continue;
            uint2 v;
            v.x = cvtpk(fmaxf(acc[ct][0], 0.f), fmaxf(acc[ct][1], 0.f));
            v.y = cvtpk(fmaxf(acc[ct][2], 0.f), fmaxf(acc[ct][3], 0.f));
            if (dead) { v.x = 0u; v.y = 0u; }
            *(uint2*)(yp + ct * 16 + g * 4) = v;
        }
    }
}

template <int D, int M2W>
__device__ __forceinline__ void conv2_tile(
        const unsigned short* __restrict__ xt, const unsigned short* __restrict__ y1,
        const unsigned short* __restrict__ wf, const float* __restrict__ bf,
        unsigned short* __restrict__ ygb, int t0, int wave, int lane,
        int writeOut, float (&sums)[3][4]) {
    const int c = lane & 15, g = lane >> 4;
    const int koff8 = (g & 1) << 3;
    const int r01off = (g >> 1) * D;
    const int r2off  = (g & 1) * D;
    short8 Wf[3][3]; float bs[3][4];
#pragma unroll
    for (int ct = 0; ct < 3; ++ct) {
#pragma unroll
        for (int sl = 0; sl < 3; ++sl)
            Wf[ct][sl] = *(const short8*)(wf + ((((3 + ct) * 3 + sl) * 64 + lane) << 3));
#pragma unroll
        for (int j = 0; j < 4; ++j) bs[ct][j] = bf[48 + ct * 16 + g * 4 + j];
    }
#pragma unroll
    for (int mi = 0; mi < M2W; ++mi) {
        int j0 = (wave * M2W + mi) << 4;
        const unsigned short* bp01 = y1 + (j0 + c + r01off) * 40 + koff8;
        const unsigned short* bp2  = y1 + (j0 + c + r2off) * 40 + 32;
        short8 B0 = *(const short8*)(bp01);
        short8 B1 = *(const short8*)(bp01 + 16);
        short8 B2 = *(const short8*)(bp2);
        floatx4 acc[3];
#pragma unroll
        for (int ct = 0; ct < 3; ++ct) {
            acc[ct] = floatx4{bs[ct][0], bs[ct][1], bs[ct][2], bs[ct][3]};
            acc[ct] = __builtin_amdgcn_mfma_f32_16x16x32_bf16(Wf[ct][0], B0, acc[ct], 0, 0, 0);
            acc[ct] = __builtin_amdgcn_mfma_f32_16x16x32_bf16(Wf[ct][1], B1, acc[ct], 0, 0, 0);
            acc[ct] = __builtin_amdgcn_mfma_f32_16x16x32_bf16(Wf[ct][2], B2, acc[ct], 0, 0, 0);
        }
        int r = j0 + c;
        const unsigned short* xrow = xt + (r + 2 * D) * CP;
        unsigned short* orow = ygb + (size_t)(t0 + r) * CP;
#pragma unroll
        for (int ct = 0; ct < 3; ++ct) {
            uint2 xv = *(const uint2*)(xrow + ct * 16 + g * 4);
            float g0 = blo(xv.x) * __builtin_amdgcn_rcpf(1.f + __expf(-acc[ct][0]));
            float g1 = bhi(xv.x) * __builtin_amdgcn_rcpf(1.f + __expf(-acc[ct][1]));
            float g2 = blo(xv.y) * __builtin_amdgcn_rcpf(1.f + __expf(-acc[ct][2]));
            float g3 = bhi(xv.y) * __builtin_amdgcn_rcpf(1.f + __expf(-acc[ct][3]));
            sums[ct][0] += g0; sums[ct][1] += g1;
            sums[ct][2] += g2; sums[ct][3] += g3;
            if (writeOut && !(ct == 2 && g >= 2)) {
                uint2 v;
                v.x = cvtpk(g0, g1);
                v.y = cvtpk(g2, g3);
                *(uint2*)(orow + ct * 16 + g * 4) = v;
            }
        }
    }
}

// ---------------------------------------------------------------------------
// 2-tile pipelined single-level block (D<=16): both tiles' staging issued
// up front; counted vmcnt keeps tile B's loads in flight under tile A's
// compute (T3/T4 minimum 2-phase pipeline).
// ---------------------------------------------------------------------------
template <int D>
__global__ __launch_bounds__(TBLK) void block2_mfma(
        const unsigned short* __restrict__ xg, unsigned short* __restrict__ yg,
        const unsigned short* __restrict__ wf_all, const float* __restrict__ bf_all,
        float* __restrict__ skipPart, const unsigned short* __restrict__ zpad,
        int blk, int writeOut) {
    constexpr int T = 256;
    constexpr int ROWS_X = T + 2 * D;
    constexpr int NCH = ROWS_X * 5;
    constexpr int NIT = (NCH + TBLK - 1) / TBLK;
    static_assert(NIT == 3, "vmcnt literal assumes NIT==3 (D<=16)");
    constexpr int XT_CH = NIT * TBLK;
    constexpr int XT_SHORTS = XT_CH * 8;
    constexpr int M1 = (T + D + 15) / 16;
    constexpr int ROWS_REAL = T + D;
    constexpr int Y1_SHORTS = M1 * 16 * 40 + 8;
    constexpr int M2W = T / (16 * NW);

    extern __shared__ char ldsraw[];
    unsigned short* xtA = (unsigned short*)ldsraw;
    unsigned short* xtB = xtA + XT_SHORTS;
    unsigned short* y1  = xtB + XT_SHORTS;
    float* stash = (float*)(y1 + Y1_SHORTS);          // [2][NW][48]

    const int dir = blockIdx.z, b = blockIdx.y, pairid = blockIdx.x;
    const int t0a = pairid * 2 * T, t0b = t0a + T;
    const int tid = threadIdx.x, lane = tid & 63, wave = tid >> 6;
    const int c = lane & 15, g = lane >> 4;

    const size_t cbase = (size_t)(dir * BATCH + b) * TT * CP;
    const unsigned short* wf = wf_all + (size_t)(dir * NBLK + blk) * WFB_PER;
    const float* bf = bf_all + (size_t)(dir * NBLK + blk) * 96;
    const unsigned short* gx = xg + cbase;
    unsigned short* ygb = yg + cbase;

    // ---- issue BOTH tiles' staging (uniform NIT chunks per wave per tile) ----
#pragma unroll
    for (int half = 0; half < 2; ++half) {
        unsigned short* xt = half ? xtB : xtA;
        const int t0 = half ? t0b : t0a;
#pragma unroll
        for (int it = 0; it < NIT; ++it) {
            int chunk = it * TBLK + wave * 64 + lane;
            unsigned row = (unsigned)chunk / 5u;
            int sub = chunk - (int)row * 5;
            int t = t0 - 2 * D + (int)row;
            const unsigned short* src = (chunk < NCH && t >= 0)
                ? (gx + (size_t)t * CP + sub * 8)
                : (zpad + ((row & 255u) * CP + sub * 8));
            gl_lds16(src, xt + (size_t)(it * TBLK + wave * 64) * 8);
        }
    }
    // wait tile A only (B's NIT=3 loads stay in flight across the barrier)
    asm volatile("s_waitcnt vmcnt(3)" ::: "memory");
    __builtin_amdgcn_sched_barrier(0);
    __builtin_amdgcn_s_barrier();

    float sums2[2][3][4];
#pragma unroll
    for (int h = 0; h < 2; ++h)
#pragma unroll
        for (int ct = 0; ct < 3; ++ct)
#pragma unroll
            for (int j = 0; j < 4; ++j) sums2[h][ct][j] = 0.f;

    // ---- tile A ----
    conv1_tile<D, M1, ROWS_REAL>(xtA, y1, wf, bf, t0a, wave, lane);
    __syncthreads();                       // drains vmcnt(0): xtB landed too
    conv2_tile<D, M2W>(xtA, y1, wf, bf, ygb, t0a, wave, lane, writeOut, sums2[0]);
    // y1 WAR barrier without draining A's stores
    asm volatile("s_waitcnt lgkmcnt(0)" ::: "memory");
    __builtin_amdgcn_sched_barrier(0);
    __builtin_amdgcn_s_barrier();

    // ---- tile B ----
    conv1_tile<D, M1, ROWS_REAL>(xtB, y1, wf, bf, t0b, wave, lane);
    __syncthreads();
    conv2_tile<D, M2W>(xtB, y1, wf, bf, ygb, t0b, wave, lane, writeOut, sums2[1]);

    // ---- reduce + stash both tiles ----
#pragma unroll
    for (int h = 0; h < 2; ++h)
#pragma unroll
        for (int ct = 0; ct < 3; ++ct)
#pragma unroll
            for (int j = 0; j < 4; ++j) {
                float v = sums2[h][ct][j];
                v += __shfl_xor(v, 1, 64);
                v += __shfl_xor(v, 2, 64);
                v += __shfl_xor(v, 4, 64);
                v += __shfl_xor(v, 8, 64);
                sums2[h][ct][j] = v;
            }
    if (c == 0) {
#pragma unroll
        for (int h = 0; h < 2; ++h)
#pragma unroll
            for (int ct = 0; ct < 3; ++ct)
#pragma unroll
                for (int j = 0; j < 4; ++j)
                    stash[(h * NW + wave) * 48 + ct * 16 + g * 4 + j] = sums2[h][ct][j];
    }
    __syncthreads();
    if (tid < CC) {
#pragma unroll
        for (int h = 0; h < 2; ++h) {
            float s = 0.f;
#pragma unroll
            for (int w = 0; w < NW; ++w) s += stash[(h * NW + w) * 48 + tid];
            skipPart[(((size_t)(blk * 2 + dir) * BATCH + b) * CC + tid) * 16
                     + pairid * 2 + h] = s;
        }
    }
}

static inline size_t lds2_bytes(int D) {
    int rows_x = 256 + 2 * D;
    int nit = (rows_x * 5 + TBLK - 1) / TBLK;
    int xt_shorts = nit * TBLK * 8;
    int m1 = (256 + D + 15) / 16;
    int y1_shorts = m1 * 16 * 40 + 8;
    return (size_t)(2 * xt_shorts + y1_shorts) * 2 + 2 * NW * 48 * 4;
}

// ---------------------------------------------------------------------------
// Single-level block (proven, unchanged). Used for D>=32.
// ---------------------------------------------------------------------------
template <int D, int TtC>
__global__ __launch_bounds__(TBLK) void block_mfma(const unsigned short* __restrict__ xg,
                                                   unsigned short* __restrict__ yg,
                                                   const unsigned short* __restrict__ wf_all,
                                                   const float* __restrict__ bf_all,
                                                   float* __restrict__ skipPart,
                                                   const unsigned short* __restrict__ zpad,
                                                   int blk, int writeOut) {
    constexpr int NW_      = TBLK / 64;
    constexpr int ROWS_X   = TtC + 2 * D;
    constexpr int NCH      = ROWS_X * 5;
    constexpr int NIT      = (NCH + TBLK - 1) / TBLK;
    constexpr int XT_SHORTS = ROWS_X * CP;
    constexpr int M1       = (TtC + D + 15) / 16;
    constexpr int ROWS_REAL = TtC + D;
    constexpr int Y1_SHORTS = M1 * 16 * Y1ST + 8;
    constexpr int M2W      = TtC / (16 * NW_);

    extern __shared__ char ldsraw[];
    unsigned short* xt = (unsigned short*)ldsraw;
    unsigned short* y1 = xt + XT_SHORTS;
    float* stash = (float*)(y1 + Y1_SHORTS);

    const int dir = blockIdx.z, b = blockIdx.y, tile = blockIdx.x;
    const int t0 = tile * TtC;
    const int tid = threadIdx.x, lane = tid & 63, wave = tid >> 6;
    const int c = lane & 15, g = lane >> 4;

    const size_t cbase = (size_t)(dir * BATCH + b) * TT * CP;
    const unsigned short* wf = wf_all + (size_t)(dir * NBLK + blk) * WFB_PER;
    const float* bf = bf_all + (size_t)(dir * NBLK + blk) * 96;

    {
        const unsigned short* gx = xg + cbase;
#pragma unroll
        for (int it = 0; it < NIT; ++it) {
            int chunk = it * TBLK + wave * 64 + lane;
            if (chunk < NCH) {
                unsigned row = (unsigned)chunk / 5u;
                int sub = chunk - (int)row * 5;
                int t = t0 - 2 * D + (int)row;
                const unsigned short* src = (t >= 0)
                    ? (gx + (size_t)t * CP + sub * 8)
                    : (zpad + (row * CP + sub * 8));
                gl_lds16(src, xt + (size_t)(it * TBLK + wave * 64) * 8);
            }
        }
    }

    short8 Wf[3][3];
#pragma unroll
    for (int ct = 0; ct < 3; ++ct)
#pragma unroll
        for (int sl = 0; sl < 3; ++sl)
            Wf[ct][sl] = *(const short8*)(wf + ((((0 * 3 + ct) * 3 + sl) * 64 + lane) << 3));
    float bs[3][4];
#pragma unroll
    for (int ct = 0; ct < 3; ++ct)
#pragma unroll
        for (int j = 0; j < 4; ++j) bs[ct][j] = bf[ct * 16 + g * 4 + j];

    __syncthreads();

    const int r01off = (g >> 1) * D;
    const int r2off  = (g & 1) * D;
    const int koff8  = (g & 1) << 3;

    for (int mt = wave; mt < M1; mt += NW_) {
        int j0 = mt << 4;
        const unsigned short* bp01 = xt + (j0 + c + r01off) * CP + koff8;
        const unsigned short* bp2  = xt + (j0 + c + r2off) * CP + 32;
        short8 B0 = *(const short8*)(bp01);
        short8 B1 = *(const short8*)(bp01 + 16);
        short8 B2 = *(const short8*)(bp2);
        floatx4 acc[3];
#pragma unroll
        for (int ct = 0; ct < 3; ++ct) {
            acc[ct] = floatx4{bs[ct][0], bs[ct][1], bs[ct][2], bs[ct][3]};
            acc[ct] = __builtin_amdgcn_mfma_f32_16x16x32_bf16(Wf[ct][0], B0, acc[ct], 0, 0, 0);
            acc[ct] = __builtin_amdgcn_mfma_f32_16x16x32_bf16(Wf[ct][1], B1, acc[ct], 0, 0, 0);
            acc[ct] = __builtin_amdgcn_mfma_f32_16x16x32_bf16(Wf[ct][2], B2, acc[ct], 0, 0, 0);
        }
        int r = j0 + c;
        bool dead = (t0 - D + r < 0) || (r >= ROWS_REAL);
        unsigned short* yp = y1 + r * Y1ST;
#pragma unroll
        for (int ct = 0; ct < 3; ++ct) {
            if (ct == 2 && g >= 2) continue;
            uint2 v;
            v.x = cvtpk(fmaxf(acc[ct][0], 0.f), fmaxf(acc[ct][1], 0.f));
            v.y = cvtpk(fmaxf(acc[ct][2], 0.f), fmaxf(acc[ct][3], 0.f));
            if (dead) { v.x = 0u; v.y = 0u; }
            *(uint2*)(yp + ct * 16 + g * 4) = v;
        }
    }
    __syncthreads();

#pragma unroll
    for (int ct = 0; ct < 3; ++ct)
#pragma unroll
        for (int sl = 0; sl < 3; ++sl)
            Wf[ct][sl] = *(const short8*)(wf + ((((1 * 3 + ct) * 3 + sl) * 64 + lane) << 3));
#pragma unroll
    for (int ct = 0; ct < 3; ++ct)
#pragma unroll
        for (int j = 0; j < 4; ++j) bs[ct][j] = bf[48 + ct * 16 + g * 4 + j];

    float sums[3][4];
#pragma unroll
    for (int ct = 0; ct < 3; ++ct)
#pragma unroll
        for (int j = 0; j < 4; ++j) sums[ct][j] = 0.f;

#pragma unroll
    for (int mi = 0; mi < M2W; ++mi) {
        int j0 = (wave * M2W + mi) << 4;
        const unsigned short* bp01 = y1 + (j0 + c + r01off) * Y1ST + koff8;
        const unsigned short* bp2  = y1 + (j0 + c + r2off) * Y1ST + 32;
        short8 B0 = *(const short8*)(bp01);
        short8 B1 = *(const short8*)(bp01 + 16);
        short8 B2 = *(const short8*)(bp2);
        floatx4 acc[3];
#pragma unroll
        for (int ct = 0; ct < 3; ++ct) {
            acc[ct] = floatx4{bs[ct][0], bs[ct][1], bs[ct][2], bs[ct][3]};
            acc[ct] = __builtin_amdgcn_mfma_f32_16x16x32_bf16(Wf[ct][0], B0, acc[ct], 0, 0, 0);
            acc[ct] = __builtin_amdgcn_mfma_f32_16x16x32_bf16(Wf[ct][1], B1, acc[ct], 0, 0, 0);
            acc[ct] = __builtin_amdgcn_mfma_f32_16x16x32_bf16(Wf[ct][2], B2, acc[ct], 0, 0, 0);
        }
        int r = j0 + c;
        const unsigned short* xrow = xt + (r + 2 * D) * CP;
        unsigned short* orow = yg + cbase + (size_t)(t0 + r) * CP;
#pragma unroll
        for (int ct = 0; ct < 3; ++ct) {
            uint2 xv = *(const uint2*)(xrow + ct * 16 + g * 4);
            float g0 = blo(xv.x) * __builtin_amdgcn_rcpf(1.f + __expf(-acc[ct][0]));
            float g1 = bhi(xv.x) * __builtin_amdgcn_rcpf(1.f + __expf(-acc[ct][1]));
            float g2 = blo(xv.y) * __builtin_amdgcn_rcpf(1.f + __expf(-acc[ct][2]));
            float g3 = bhi(xv.y) * __builtin_amdgcn_rcpf(1.f + __expf(-acc[ct][3]));
            sums[ct][0] += g0; sums[ct][1] += g1;
            sums[ct][2] += g2; sums[ct][3] += g3;
            if (writeOut && !(ct == 2 && g >= 2)) {
                uint2 v;
                v.x = cvtpk(g0, g1);
                v.y = cvtpk(g2, g3);
                *(uint2*)(orow + ct * 16 + g * 4) = v;
            }
        }
    }
#pragma unroll
    for (int ct = 0; ct < 3; ++ct)
#pragma unroll
        for (int j = 0; j < 4; ++j) {
            float v = sums[ct][j];
            v += __shfl_xor(v, 1, 64);
            v += __shfl_xor(v, 2, 64);
            v += __shfl_xor(v, 4, 64);
            v += __shfl_xor(v, 8, 64);
            sums[ct][j] = v;
        }
    if (c == 0) {
#pragma unroll
        for (int ct = 0; ct < 3; ++ct)
#pragma unroll
            for (int j = 0; j < 4; ++j)
                stash[wave * 48 + ct * 16 + g * 4 + j] = sums[ct][j];
    }
    __syncthreads();
    if (tid < CC) {
        float s = 0.f;
#pragma unroll
        for (int w = 0; w < NW_; ++w) s += stash[w * 48 + tid];
        skipPart[(((size_t)(blk * 2 + dir) * BATCH + b) * CC + tid) * 16 + tile] = s;
    }
}

static inline size_t lds_bytes_for(int D, int Tt) {
    int rows_x = Tt + 2 * D;
    int xt_shorts = rows_x * CP;
    int m1 = (Tt + D + 15) / 16;
    int y1_shorts = m1 * 16 * Y1ST + 8;
    return (size_t)(xt_shorts + y1_shorts) * 2 + (TBLK / 64) * 48 * 4;
}

// ---------------------------------------------------------------------------
// Tail: sums ALL 16 tile slots (unused slots zeroed by memset).
// ---------------------------------------------------------------------------
__global__ __launch_bounds__(64) void tail_kernel(const float* __restrict__ skipPart,
                                                  const float* __restrict__ wl,
                                                  const float* __restrict__ cw,
                                                  const float* __restrict__ cb,
                                                  float* __restrict__ out) {
    __shared__ float xs[CC];
    int b = blockIdx.x;
    int cth = threadIdx.x;
    if (cth < CC) {
        float x2 = 0.f;
        for (int i = 0; i < NBLK; ++i) {
            float wli = wl[i] * (1.0f / TT);
            for (int dirn = 0; dirn < 2; ++dirn) {
                const float* sp = skipPart + (((size_t)(i * 2 + dirn) * BATCH + b) * CC + cth) * 16;
                float s = 0.f;
#pragma unroll
                for (int tl = 0; tl < 16; ++tl) s += sp[tl];
                x2 = fmaf(s, wli, x2);
            }
        }
        xs[cth] = x2;
    }
    __syncthreads();
    if (threadIdx.x == 0) {
        float lg[NCLS];
        float mx = -1e30f;
        for (int o = 0; o < NCLS; ++o) {
            float a = cb[o];
#pragma unroll
            for (int cc2 = 0; cc2 < CC; ++cc2) a = fmaf(cw[o * CC + cc2], xs[cc2], a);
            lg[o] = a;
            mx = fmaxf(mx, a);
        }
        float se = 0.f;
        for (int o = 0; o < NCLS; ++o) se += expf(lg[o] - mx);
        float lse = logf(se) + mx;
        for (int o = 0; o < NCLS; ++o) out[b * NCLS + o] = lg[o] - lse;
    }
}

// ---------------------------------------------------------------------------
extern "C" void kernel_launch(void* const* d_in, const int* in_sizes, int n_in,
                              void* d_out, int out_size, void* d_ws, size_t ws_size,
                              hipStream_t stream) {
    const float* inputs = (const float*)d_in[0];
    const float* c1w    = (const float*)d_in[1];
    const float* c1b    = (const float*)d_in[2];
    const float* fw_w   = (const float*)d_in[3];
    const float* fw_b   = (const float*)d_in[4];
    const float* fw_g   = (const float*)d_in[5];
    const float* fw_be  = (const float*)d_in[6];
    const float* fw_m   = (const float*)d_in[7];
    const float* fw_v   = (const float*)d_in[8];
    const float* bw_w   = (const float*)d_in[9];
    const float* bw_b   = (const float*)d_in[10];
    const float* bw_g   = (const float*)d_in[11];
    const float* bw_be  = (const float*)d_in[12];
    const float* bw_m   = (const float*)d_in[13];
    const float* bw_v   = (const float*)d_in[14];
    const float* wl     = (const float*)d_in[15];
    const float* clsw   = (const float*)d_in[16];
    const float* clsb   = (const float*)d_in[17];

    const size_t bufsz = (size_t)2 * BATCH * TT * CP;
    unsigned short* buf0 = (unsigned short*)d_ws;
    unsigned short* buf1 = buf0 + bufsz;
    float* skip = (float*)(buf1 + bufsz);
    const size_t skipsz = (size_t)NBLK * 2 * BATCH * CC * 16;
    unsigned short* wfb = (unsigned short*)(skip + skipsz);
    float* bfb = (float*)(wfb + WFB_TOTAL);
    unsigned short* wff = (unsigned short*)(bfb + BFB_TOTAL);
    float* bff = (float*)(wff + WFF_TOTAL);
    unsigned short* zpad = (unsigned short*)(bff + BFF_TOTAL);

    hipMemsetAsync(zpad, 0, ZPAD_SHORTS * sizeof(unsigned short), stream);
    hipMemsetAsync(skip, 0, skipsz * sizeof(float), stream);

    {
        int tot = WFB_TOTAL + BFB_TOTAL + WFF_TOTAL + BFF_TOTAL;
        fold_kernel<<<(tot + 255) / 256, 256, 0, stream>>>(
            fw_w, fw_b, fw_g, fw_be, fw_m, fw_v,
            bw_w, bw_b, bw_g, bw_be, bw_m, bw_v, c1w, c1b,
            wfb, bfb, wff, bff);
    }

    // level 0 with fused front conv: raw f32 -> buf0
    {
        size_t lds0 = (size_t)(272 * CP + 17 * 16 * Y1ST + 8) * 2 + (TBLK / 64) * 48 * 4 + 64;
        block0_mfma<<<dim3(TT / 256, BATCH, 2), TBLK, lds0, stream>>>(
            inputs, wfb, bfb, wff, bff, buf0, skip);
    }

    // levels 1-4: 2-tile pipelined (counted vmcnt)
    block2_mfma<2><<<dim3(TT / 512, BATCH, 2), TBLK, lds2_bytes(2), stream>>>(
        buf0, buf1, wfb, bfb, skip, zpad, 1, 1);
    block2_mfma<4><<<dim3(TT / 512, BATCH, 2), TBLK, lds2_bytes(4), stream>>>(
        buf1, buf0, wfb, bfb, skip, zpad, 2, 1);
    block2_mfma<8><<<dim3(TT / 512, BATCH, 2), TBLK, lds2_bytes(8), stream>>>(
        buf0, buf1, wfb, bfb, skip, zpad, 3, 1);
    block2_mfma<16><<<dim3(TT / 512, BATCH, 2), TBLK, lds2_bytes(16), stream>>>(
        buf1, buf0, wfb, bfb, skip, zpad, 4, 1);

    // levels 5-7: proven single-tile path
    block_mfma<32, 256><<<dim3(TT / 256, BATCH, 2), TBLK, lds_bytes_for(32, 256), stream>>>(
        buf0, buf1, wfb, bfb, skip, zpad, 5, 1);
    block_mfma<64, 256><<<dim3(TT / 256, BATCH, 2), TBLK, lds_bytes_for(64, 256), stream>>>(
        buf1, buf0, wfb, bfb, skip, zpad, 6, 1);
    block_mfma<128, 256><<<dim3(TT / 256, BATCH, 2), TBLK, lds_bytes_for(128, 256), stream>>>(
        buf0, buf1, wfb, bfb, skip, zpad, 7, 0);

    tail_kernel<<<BATCH, 64, 0, stream>>>(skip, wl, clsw, clsb, (float*)d_out);
}